// Round 1
// baseline (992.637 us; speedup 1.0000x reference)
//
#include <hip/hip_runtime.h>
#include <math.h>

#define B_   128
#define S_   1024
#define DIN  1024
#define NQ_  8
#define NB_  256
#define ROWS (B_ * S_)  // 131072

// ---------------------------------------------------------------------------
// K0: fold the two output GEMMs:  uncertainty = sigmoid(measured @ W2^T + b2)
//     W2[i][j] = sum_k unc_w[i][k] * meas_w[k][j]   (256 x 8)
//     b2[i]    = unc_b[i] + sum_k unc_w[i][k] * meas_b[k]
// ---------------------------------------------------------------------------
__global__ __launch_bounds__(256) void k0_compose(
    const float* __restrict__ meas_w, const float* __restrict__ meas_b,
    const float* __restrict__ unc_w, const float* __restrict__ unc_b,
    float* __restrict__ W2, float* __restrict__ b2) {
  int i = threadIdx.x;  // 0..255
  float acc[NQ_] = {0.f, 0.f, 0.f, 0.f, 0.f, 0.f, 0.f, 0.f};
  float accb = 0.f;
  for (int k = 0; k < NB_; ++k) {
    float u = unc_w[i * NB_ + k];
#pragma unroll
    for (int j = 0; j < NQ_; ++j) acc[j] += u * meas_w[k * NQ_ + j];
    accb += u * meas_b[k];
  }
#pragma unroll
  for (int j = 0; j < NQ_; ++j) W2[i * NQ_ + j] = acc[j];
  b2[i] = unc_b[i] + accb;
}

// ---------------------------------------------------------------------------
// K1: per row r of x[131072][1024]: 16 dot products (8 amp + 8 phase),
//     then tanh / sigmoid*2pi / sincos -> real_part, imag_part [row][8].
//     Thread = row. Weight indices are block-uniform -> scalar loads (s_load),
//     x streams through vector path (float4, L1 reuses the 4k-strided lines).
// ---------------------------------------------------------------------------
__global__ __launch_bounds__(256) void k1_proj(
    const float* __restrict__ x,
    const float* __restrict__ amp_w, const float* __restrict__ amp_b,
    const float* __restrict__ phase_w, const float* __restrict__ phase_b,
    float* __restrict__ rp, float* __restrict__ ip) {
  int row = blockIdx.x * blockDim.x + threadIdx.x;  // 0..131071
  const float4* xr = (const float4*)(x + (size_t)row * DIN);
  float acc[16];
#pragma unroll
  for (int j = 0; j < 16; ++j) acc[j] = 0.f;

  for (int k4 = 0; k4 < DIN / 4; ++k4) {
    float4 xv = xr[k4];
#pragma unroll
    for (int kk = 0; kk < 4; ++kk) {
      int k = k4 * 4 + kk;  // block-uniform
      float xk = (kk == 0) ? xv.x : (kk == 1) ? xv.y : (kk == 2) ? xv.z : xv.w;
#pragma unroll
      for (int j = 0; j < 8; ++j) {
        acc[j]     += xk * amp_w[j * DIN + k];
        acc[8 + j] += xk * phase_w[j * DIN + k];
      }
    }
  }

  float out_r[8], out_i[8];
  const float two_pi = 6.28318530717958647692f;
#pragma unroll
  for (int j = 0; j < 8; ++j) {
    float a  = tanhf(acc[j] + amp_b[j]);
    float ph = two_pi / (1.f + expf(-(acc[8 + j] + phase_b[j])));
    float s, c;
    sincosf(ph, &s, &c);
    out_r[j] = a * c;
    out_i[j] = a * s;
  }
  float4* rp4 = (float4*)(rp + (size_t)row * NQ_);
  float4* ip4 = (float4*)(ip + (size_t)row * NQ_);
  rp4[0] = make_float4(out_r[0], out_r[1], out_r[2], out_r[3]);
  rp4[1] = make_float4(out_r[4], out_r[5], out_r[6], out_r[7]);
  ip4[0] = make_float4(out_i[0], out_i[1], out_i[2], out_i[3]);
  ip4[1] = make_float4(out_i[4], out_i[5], out_i[6], out_i[7]);
}

// ---------------------------------------------------------------------------
// K2: MHA over L=128 (the B dim) for each n (the S dim), E=8, 4 heads, Dh=2.
//     One block per n (128 threads), both real & imag parts.
//     Stage A: thread=l computes qkv (in_proj). Stage B: thread=(part,head,
//     8-row block) does softmax(QK^T/sqrt(2))V with k/v from LDS (each LDS
//     read amortized over 8 rows). Stage C: thread=l does out_proj for both
//     parts and writes measured = sqrt(er^2 + ei^2).
//     No max-subtraction: |score| <= 2*(8/sqrt(8))^2/sqrt(2) ~= 11.3, exp safe.
// ---------------------------------------------------------------------------
__global__ __launch_bounds__(128) void k2_attn(
    const float* __restrict__ rp, const float* __restrict__ ip,
    const float* __restrict__ in_w, const float* __restrict__ in_b,
    const float* __restrict__ out_w, const float* __restrict__ out_b,
    float* __restrict__ measured) {
  int n = blockIdx.x;
  int tid = threadIdx.x;

  __shared__ float q_lds[2][128][9];    // pad 9: stride coprime with 32 banks
  __shared__ float kv_lds[2][128][17];  // [0..7]=k, [8..15]=v, pad 17
  __shared__ float o_lds[2][128][9];

  // ---- stage A: qkv projection, thread = l ----
  {
    int l = tid;
#pragma unroll
    for (int p = 0; p < 2; ++p) {
      const float* src = (p == 0 ? rp : ip) + (size_t)l * (S_ * NQ_) + (size_t)n * NQ_;
      float xv[8];
#pragma unroll
      for (int j = 0; j < 8; ++j) xv[j] = src[j];
#pragma unroll
      for (int c = 0; c < 24; ++c) {
        float acc = in_b[c];
#pragma unroll
        for (int j = 0; j < 8; ++j) acc += in_w[c * 8 + j] * xv[j];
        if (c < 8) q_lds[p][l][c] = acc;
        else       kv_lds[p][l][c - 8] = acc;
      }
    }
  }
  __syncthreads();

  // ---- stage B: attention, thread = (p, h, lb) with 8 rows each ----
  {
    int p = tid >> 6, h = (tid >> 4) & 3, lb = tid & 15;
    float q0[8], q1[8], o0[8], o1[8], ssum[8];
#pragma unroll
    for (int r = 0; r < 8; ++r) {
      q0[r] = q_lds[p][lb * 8 + r][2 * h];
      q1[r] = q_lds[p][lb * 8 + r][2 * h + 1];
      o0[r] = 0.f; o1[r] = 0.f; ssum[r] = 0.f;
    }
    const float scale = 0.70710678118654752440f;  // 1/sqrt(Dh)
    for (int m = 0; m < 128; ++m) {
      float k0 = kv_lds[p][m][2 * h];
      float k1 = kv_lds[p][m][2 * h + 1];
      float v0 = kv_lds[p][m][8 + 2 * h];
      float v1 = kv_lds[p][m][8 + 2 * h + 1];
#pragma unroll
      for (int r = 0; r < 8; ++r) {
        float s = (q0[r] * k0 + q1[r] * k1) * scale;
        float e = expf(s);
        ssum[r] += e;
        o0[r] += e * v0;
        o1[r] += e * v1;
      }
    }
#pragma unroll
    for (int r = 0; r < 8; ++r) {
      float inv = 1.f / ssum[r];
      o_lds[p][lb * 8 + r][2 * h]     = o0[r] * inv;
      o_lds[p][lb * 8 + r][2 * h + 1] = o1[r] * inv;
    }
  }
  __syncthreads();

  // ---- stage C: out_proj + measured, thread = l ----
  {
    int l = tid;
    float res[2][8];
#pragma unroll
    for (int p = 0; p < 2; ++p) {
      float ov[8];
#pragma unroll
      for (int c = 0; c < 8; ++c) ov[c] = o_lds[p][l][c];
#pragma unroll
      for (int j = 0; j < 8; ++j) {
        float acc = out_b[j];
#pragma unroll
        for (int c = 0; c < 8; ++c) acc += out_w[j * 8 + c] * ov[c];
        res[p][j] = acc;
      }
    }
    float* dst = measured + (size_t)l * (S_ * NQ_) + (size_t)n * NQ_;
#pragma unroll
    for (int j = 0; j < 8; ++j)
      dst[j] = sqrtf(res[0][j] * res[0][j] + res[1][j] * res[1][j]);
  }
}

// ---------------------------------------------------------------------------
// K3: per row: compressed[i] = m . meas_w[i] + meas_b[i]  (written to out0)
//              uncertainty[i] = sigmoid(m . W2[i] + b2[i]) (written to out1)
//     Thread = i (256), 64 rows per block. m loads are block-uniform (scalar
//     path); stores fully coalesced. Write-bound (256 MB).
// ---------------------------------------------------------------------------
__global__ __launch_bounds__(256) void k3_out(
    const float* __restrict__ measured,
    const float* __restrict__ meas_w, const float* __restrict__ meas_b,
    const float* __restrict__ W2, const float* __restrict__ b2,
    float* __restrict__ out_c, float* __restrict__ out_u) {
  int i = threadIdx.x;
  float w1[8], w2[8];
#pragma unroll
  for (int j = 0; j < 8; ++j) {
    w1[j] = meas_w[i * 8 + j];
    w2[j] = W2[i * 8 + j];
  }
  float b1 = meas_b[i], bu = b2[i];
  int r0 = blockIdx.x * 64;
  for (int rr = 0; rr < 64; ++rr) {
    int r = r0 + rr;
    const float* m = measured + (size_t)r * NQ_;  // block-uniform -> s_load
    float mv[8];
#pragma unroll
    for (int j = 0; j < 8; ++j) mv[j] = m[j];
    float c = b1, u = bu;
#pragma unroll
    for (int j = 0; j < 8; ++j) {
      c += w1[j] * mv[j];
      u += w2[j] * mv[j];
    }
    out_c[(size_t)r * NB_ + i] = c;
    out_u[(size_t)r * NB_ + i] = 1.f / (1.f + expf(-u));
  }
}

// ---------------------------------------------------------------------------
extern "C" void kernel_launch(void* const* d_in, const int* in_sizes, int n_in,
                              void* d_out, int out_size, void* d_ws, size_t ws_size,
                              hipStream_t stream) {
  (void)in_sizes; (void)n_in; (void)out_size; (void)ws_size;
  const float* x       = (const float*)d_in[0];
  const float* amp_w   = (const float*)d_in[1];
  const float* amp_b   = (const float*)d_in[2];
  const float* phase_w = (const float*)d_in[3];
  const float* phase_b = (const float*)d_in[4];
  const float* in_w    = (const float*)d_in[5];
  const float* in_b    = (const float*)d_in[6];
  const float* out_w   = (const float*)d_in[7];
  const float* out_b   = (const float*)d_in[8];
  const float* meas_w  = (const float*)d_in[9];
  const float* meas_b  = (const float*)d_in[10];
  const float* unc_w   = (const float*)d_in[11];
  const float* unc_b   = (const float*)d_in[12];

  float* ws       = (float*)d_ws;
  float* rp       = ws;                   // 131072*8
  float* ip       = rp + 1048576;         // 131072*8
  float* measured = ip + 1048576;         // 131072*8
  float* W2       = measured + 1048576;   // 256*8
  float* b2       = W2 + 2048;            // 256
  float* out_c    = (float*)d_out;
  float* out_u    = out_c + (size_t)ROWS * NB_;

  hipLaunchKernelGGL(k0_compose, dim3(1), dim3(256), 0, stream,
                     meas_w, meas_b, unc_w, unc_b, W2, b2);
  hipLaunchKernelGGL(k1_proj, dim3(ROWS / 256), dim3(256), 0, stream,
                     x, amp_w, amp_b, phase_w, phase_b, rp, ip);
  hipLaunchKernelGGL(k2_attn, dim3(S_), dim3(128), 0, stream,
                     rp, ip, in_w, in_b, out_w, out_b, measured);
  hipLaunchKernelGGL(k3_out, dim3(ROWS / 64), dim3(256), 0, stream,
                     measured, meas_w, meas_b, W2, b2, out_c, out_u);
}